// Round 1
// baseline (271.507 us; speedup 1.0000x reference)
//
#include <hip/hip_runtime.h>
#include <hip/hip_bf16.h>

typedef __attribute__((ext_vector_type(8))) short short8;   // 8 bf16 = 4 VGPRs (MFMA A/B frag)
typedef __attribute__((ext_vector_type(4))) short short4v;  // 4 bf16 = 8 B
typedef __attribute__((ext_vector_type(4))) float floatx4;  // MFMA C/D frag

#define MFMA(a, b, c) __builtin_amdgcn_mfma_f32_16x16x32_bf16((a), (b), (c), 0, 0, 0)

// fp32 -> bf16, round-to-nearest-even (bit trick; inputs are finite)
__device__ __forceinline__ short f2bf(float f) {
    unsigned u = __float_as_uint(f);
    u += 0x7fffu + ((u >> 16) & 1u);
    return (short)(u >> 16);
}

__device__ __forceinline__ short8 pack_bf16(floatx4 a, floatx4 b) {
    short8 r;
    r[0] = f2bf(a.x); r[1] = f2bf(a.y); r[2] = f2bf(a.z); r[3] = f2bf(a.w);
    r[4] = f2bf(b.x); r[5] = f2bf(b.y); r[6] = f2bf(b.z); r[7] = f2bf(b.w);
    return r;
}

// ---------------------------------------------------------------------------
// Cayley via Neumann/Horner series on one block (256 threads, 4 waves).
//   B = skew(X)/2 (||B||_2 ~ 0.16);  C = I + 2*(B + B^2 + ...)
// NSTEP=6 -> truncation ~4e-5, far below bf16 rounding.
// mode 0: write C row-major bf16 (B-operand array)
// mode 1: write C^T * diag bf16  (A-operand array, diag folded)
// ---------------------------------------------------------------------------
__device__ void cayley64(const float* __restrict__ X, const float* __restrict__ dg,
                         short* outArr, int mode,
                         short* Brow, float* Bcol, short* T0, short* T1, int tid)
{
    int i0 = (tid * 16) >> 6;
    int j0 = (tid * 16) & 63;
#pragma unroll
    for (int s = 0; s < 16; ++s) {
        int i = i0, j = j0 + s;
        float b = 0.f;
        if (i > j)      b =  0.5f * X[i * 64 + j];
        else if (i < j) b = -0.5f * X[j * 64 + i];
        Brow[i * 72 + j] = f2bf(b);
        Bcol[j * 68 + i] = b;
        T0[j * 72 + i]   = f2bf(b);
    }
    __syncthreads();

    int lane = tid & 63, w = tid >> 6, m = lane & 15, q = lane >> 4;
    int arow = (w * 16 + m) * 72;
    short8 a0 = *(const short8*)&Brow[arow + q * 8];
    short8 a1 = *(const short8*)&Brow[arow + 32 + q * 8];

    short* Tbuf[2] = {T0, T1};
    int cur = 0;
    const int NSTEP = 6;
    for (int step = 0; step < NSTEP; ++step) {
        bool last = (step == NSTEP - 1);
        short* Tr = Tbuf[cur];
        short* Tw = Tbuf[cur ^ 1];
#pragma unroll
        for (int c = 0; c < 4; ++c) {
            int coff = c * 16 + m;
            short8 b0 = *(const short8*)&Tr[coff * 72 + q * 8];
            short8 b1 = *(const short8*)&Tr[coff * 72 + 32 + q * 8];
            floatx4 acc = {0.f, 0.f, 0.f, 0.f};
            acc = MFMA(a0, b0, acc);
            acc = MFMA(a1, b1, acc);
            int row0 = w * 16 + q * 4;
            floatx4 badd = *(const floatx4*)&Bcol[coff * 68 + row0];
            floatx4 t = badd + acc;                 // T_new = B + B*T_old
            if (!last) {
                short4v pk = { f2bf(t.x), f2bf(t.y), f2bf(t.z), f2bf(t.w) };
                *(short4v*)&Tw[coff * 72 + row0] = pk;
            } else {
                int col = coff;
                floatx4 cv;
                cv.x = ((row0 + 0) == col ? 1.f : 0.f) + 2.f * t.x;
                cv.y = ((row0 + 1) == col ? 1.f : 0.f) + 2.f * t.y;
                cv.z = ((row0 + 2) == col ? 1.f : 0.f) + 2.f * t.z;
                cv.w = ((row0 + 3) == col ? 1.f : 0.f) + 2.f * t.w;
                if (mode == 0) {
                    outArr[(row0 + 0) * 72 + col] = f2bf(cv.x);
                    outArr[(row0 + 1) * 72 + col] = f2bf(cv.y);
                    outArr[(row0 + 2) * 72 + col] = f2bf(cv.z);
                    outArr[(row0 + 3) * 72 + col] = f2bf(cv.w);
                } else {
                    floatx4 dv = *(const floatx4*)&dg[row0];
                    short4v pk = { f2bf(cv.x * dv.x), f2bf(cv.y * dv.y),
                                   f2bf(cv.z * dv.z), f2bf(cv.w * dv.w) };
                    *(short4v*)&outArr[col * 72 + row0] = pk;
                }
            }
        }
        __syncthreads();
        cur ^= 1;
    }
}

// ---------------------------------------------------------------------------
// k_prep: 2 blocks. Block 0 -> m_left^T, block 1 -> m_right^T (bf16 row-major)
// ---------------------------------------------------------------------------
__global__ __launch_bounds__(256) void k_prep(
        const float* __restrict__ u_l, const float* __restrict__ v_l, const float* __restrict__ dg_l,
        const float* __restrict__ u_r, const float* __restrict__ v_r, const float* __restrict__ dg_r,
        short* __restrict__ wsOut)
{
    __shared__ __align__(16) short Brow[64 * 72];
    __shared__ __align__(16) float Bcol[64 * 68];
    __shared__ __align__(16) short T0[64 * 72];
    __shared__ __align__(16) short T1[64 * 72];
    __shared__ __align__(16) short CvA[64 * 72];
    __shared__ __align__(16) short CuB[64 * 72];

    int tid = threadIdx.x;
    const float* U  = (blockIdx.x == 0) ? u_l  : u_r;
    const float* V  = (blockIdx.x == 0) ? v_l  : v_r;
    const float* DG = (blockIdx.x == 0) ? dg_l : dg_r;
    short* outT = wsOut + blockIdx.x * 4096;

    cayley64(V, DG, CvA, 1, Brow, Bcol, T0, T1, tid);
    __syncthreads();
    cayley64(U, DG, CuB, 0, Brow, Bcol, T0, T1, tid);
    __syncthreads();

    int lane = tid & 63, w = tid >> 6, m = lane & 15, q = lane >> 4;
    int arow = (w * 16 + m) * 72;
    short8 a0 = *(const short8*)&CvA[arow + q * 8];
    short8 a1 = *(const short8*)&CvA[arow + 32 + q * 8];
#pragma unroll
    for (int c = 0; c < 4; ++c) {
        short8 b0 = *(const short8*)&CuB[(c * 16 + m) * 72 + q * 8];
        short8 b1 = *(const short8*)&CuB[(c * 16 + m) * 72 + 32 + q * 8];
        floatx4 acc = {0.f, 0.f, 0.f, 0.f};
        acc = MFMA(a0, b0, acc);
        acc = MFMA(a1, b1, acc);
        int row0 = w * 16 + q * 4, col = c * 16 + m;
        outT[(row0 + 0) * 64 + col] = f2bf(acc.x);
        outT[(row0 + 1) * 64 + col] = f2bf(acc.y);
        outT[(row0 + 2) * 64 + col] = f2bf(acc.z);
        outT[(row0 + 3) * 64 + col] = f2bf(acc.w);
    }
}

// ---------------------------------------------------------------------------
// k_main v4: out_n = P @ (x_n * dscale) @ Q
//   BARRIER-FREE: each wave owns whole matrices. Per matrix:
//     phase A (x4 chunks of 16 rows): load chunk (prefetched 1 deep),
//       scale by dscale (re-read per chunk; 16 KB table is L1-resident),
//       8 MFMAs -> S row-tile, write S^T slice to this wave's PRIVATE LDS.
//     phase B: 8 ds_read_b128 (B-frags shared across row-tiles) + 32 MFMAs,
//       nontemporal fp32 stores (out is write-once; keep x in L3).
//   No s_barrier anywhere -> no convoying; loads stay in flight continuously.
//   LDS 4x9216 B = 36864 -> 4 blocks/CU; target VGPR <= 128 -> 16 waves/CU,
//   each ~4 KB outstanding => ~64 KB in flight per CU >> BW*latency (~9 KB).
// ---------------------------------------------------------------------------
#define MPW 2   // matrices per wave; grid = N / (4 waves * MPW) = 1024 blocks
                // (>= 4 blocks/CU resident across 256 CUs in one generation)

__global__ __launch_bounds__(256) void k_main(
        const float* __restrict__ x, const float* __restrict__ dsc,
        const short* __restrict__ mLT, const short* __restrict__ mRT,
        float* __restrict__ out, int N)
{
    __shared__ __align__(16) short ST[4][64 * 72];   // per-wave private S^T

    const int tid = threadIdx.x;
    const int w = tid >> 6, lane = tid & 63, m = lane & 15, q = lane >> 4;
    short* st = ST[w];

    // P (A-operand) and Q^T (B-operand) fragments, all 4 tiles each, in regs
    short8 pf[4][2], qf[4][2];
#pragma unroll
    for (int r = 0; r < 4; ++r) {
        pf[r][0] = *(const short8*)&mLT[(r * 16 + m) * 64 + q * 8];
        pf[r][1] = *(const short8*)&mLT[(r * 16 + m) * 64 + 32 + q * 8];
        qf[r][0] = *(const short8*)&mRT[(r * 16 + m) * 64 + q * 8];
        qf[r][1] = *(const short8*)&mRT[(r * 16 + m) * 64 + 32 + q * 8];
    }

    const int gw = blockIdx.x * 4 + w;
    const long n0 = (long)gw * MPW;
    if (n0 >= N) return;
    const int nmat = ((long)N - n0 >= MPW) ? MPW : (int)((long)N - n0);
    const int nch  = nmat * 4;             // 16-row chunks in this wave's stream

    const int loff = m * 64 + q * 8;       // lane's float offset within a chunk
    const float* xw = x + (size_t)n0 * 4096 + loff;   // contiguous 16/32 KB stream
    float* ow = out + (size_t)n0 * 4096;

    // prefetch chunk 0
    floatx4 cx0 = *(const floatx4*)&xw[0];
    floatx4 cx1 = *(const floatx4*)&xw[4];
    floatx4 cx2 = *(const floatx4*)&xw[32];
    floatx4 cx3 = *(const floatx4*)&xw[36];

    for (int i = 0; i < nmat; ++i) {
        // ---- phase A: 4 chunks -> S^T in private LDS
#pragma unroll
        for (int rt = 0; rt < 4; ++rt) {
            const int cc = i * 4 + rt;
            const bool pfok = (cc + 1 < nch);
            floatx4 nx0, nx1, nx2, nx3;
            if (pfok) {    // issue next chunk's loads before any compute/waits
                const float* xn = xw + (size_t)(cc + 1) * 1024;
                nx0 = *(const floatx4*)&xn[0];
                nx1 = *(const floatx4*)&xn[4];
                nx2 = *(const floatx4*)&xn[32];
                nx3 = *(const floatx4*)&xn[36];
            }
            // dscale for this chunk (L1-hot; 16 KB shared by all waves)
            const float* dp = dsc + rt * 1024 + loff;
            floatx4 d0 = *(const floatx4*)&dp[0];
            floatx4 d1 = *(const floatx4*)&dp[4];
            floatx4 d2 = *(const floatx4*)&dp[32];
            floatx4 d3 = *(const floatx4*)&dp[36];

            // scale + convert A-frags (identical numerics to v3)
            short8 a0 = pack_bf16(cx0 * d0, cx1 * d1);   // k = 0..31
            short8 a1 = pack_bf16(cx2 * d2, cx3 * d3);   // k = 32..63

            // S row-tile rt, all 4 col-tiles; write S^T slice
#pragma unroll
            for (int c = 0; c < 4; ++c) {
                floatx4 s = {0.f, 0.f, 0.f, 0.f};
                s = MFMA(a0, qf[c][0], s);
                s = MFMA(a1, qf[c][1], s);
                short4v pk = { f2bf(s.x), f2bf(s.y), f2bf(s.z), f2bf(s.w) };
                *(short4v*)&st[(c * 16 + m) * 72 + rt * 16 + q * 4] = pk;
            }
            if (pfok) { cx0 = nx0; cx1 = nx1; cx2 = nx2; cx3 = nx3; }
        }

        // ---- phase B: out = P @ S (within-wave; compiler orders via lgkmcnt)
        float* op = ow + (size_t)i * 4096;
#pragma unroll
        for (int c2 = 0; c2 < 4; ++c2) {
            short8 b0 = *(const short8*)&st[(c2 * 16 + m) * 72 + q * 8];
            short8 b1 = *(const short8*)&st[(c2 * 16 + m) * 72 + 32 + q * 8];
            const int col = c2 * 16 + m;
#pragma unroll
            for (int r = 0; r < 4; ++r) {
                floatx4 o = {0.f, 0.f, 0.f, 0.f};
                o = MFMA(pf[r][0], b0, o);
                o = MFMA(pf[r][1], b1, o);
                const int row0 = r * 16 + q * 4;
                __builtin_nontemporal_store(o.x, &op[(row0 + 0) * 64 + col]);
                __builtin_nontemporal_store(o.y, &op[(row0 + 1) * 64 + col]);
                __builtin_nontemporal_store(o.z, &op[(row0 + 2) * 64 + col]);
                __builtin_nontemporal_store(o.w, &op[(row0 + 3) * 64 + col]);
            }
        }
    }
}

extern "C" void kernel_launch(void* const* d_in, const int* in_sizes, int n_in,
                              void* d_out, int out_size, void* d_ws, size_t ws_size,
                              hipStream_t stream) {
    const float* x    = (const float*)d_in[0];
    const float* u_l  = (const float*)d_in[1];
    const float* v_l  = (const float*)d_in[2];
    const float* dg_l = (const float*)d_in[3];
    const float* u_r  = (const float*)d_in[4];
    const float* v_r  = (const float*)d_in[5];
    const float* dg_r = (const float*)d_in[6];
    const float* dsc  = (const float*)d_in[7];
    float* out = (float*)d_out;
    short* ws  = (short*)d_ws;   // [0..4095]=m_left^T bf16, [4096..8191]=m_right^T bf16

    int N = in_sizes[0] / 4096;  // 8192 matrices of 64x64

    hipLaunchKernelGGL(k_prep, dim3(2), dim3(256), 0, stream,
                       u_l, v_l, dg_l, u_r, v_r, dg_r, ws);
    int grid = (N + MPW * 4 - 1) / (MPW * 4);
    hipLaunchKernelGGL(k_main, dim3(grid), dim3(256), 0, stream,
                       x, dsc, ws, ws + 4096, out, N);
}